// Round 1
// 174.831 us; speedup vs baseline: 1.1011x; 1.1011x over previous
//
#include <hip/hip_runtime.h>

// Problem constants (fixed by setup_inputs: 4096x4096 fp32).
#define H 4096
#define W 4096
#define TILE 64
#define PADR 7                    // max k = 15 -> radius 7
#define PT (TILE + 2 * PADR)      // 78 padded tile extent
#define PROWS (PT + 1)            // 79 (row/col 0 are zeros of the prefix sum)
#define STRIDE 81                 // odd stride: scan lanes spread over all 32 banks
#define ARENA (PROWS * STRIDE)    // 6399 dwords
#define NCHUNK ((ARENA + 63) / 64) // 100 chunks of 64 dwords -> covers 6400 dwords

// Async global->LDS: dest is wave-uniform base + lane*4 (linear), source is
// per-lane (arbitrary, clamped). Guards/junk positions get garbage, zeroed later.
#define GLOAD_LDS4(gp, lp) __builtin_amdgcn_global_load_lds(                 \
    (const __attribute__((address_space(1))) void*)(gp),                     \
    (__attribute__((address_space(3))) void*)(lp), 4, 0, 0)

__global__ __launch_bounds__(256) void multi_box_kernel(
    const float* __restrict__ x,
    const float* __restrict__ base,
    float* __restrict__ out)
{
    __shared__ float P[NCHUNK * 64];  // 25.6 KB -> 6 blocks/CU by LDS

    const int tid  = threadIdx.x;
    const int lane = tid & 63;
    const int wv   = tid >> 6;
    const int bx0  = blockIdx.x * TILE;
    const int by0  = blockIdx.y * TILE;

    // ---- Phase 1: async staging. LDS dword d maps to padded-tile
    // (row = d/81, col = d%81); data region rows 1..78 / cols 1..78 gets the
    // clamped (replicate-padded) tile; guard row 0 / col 0 and junk cols 79..80
    // receive harmless in-bounds garbage (guards re-zeroed in phase 2b).
    // 25 async issues per wave, ONE vmcnt drain at the barrier.
    #pragma unroll
    for (int c0 = 0; c0 < NCHUNK; c0 += 4) {
        const int c   = c0 + wv;               // wave-uniform chunk id
        const int d   = c * 64 + lane;
        const int row = d / 81;                // magic-mul, no real divide
        const int col = d - row * 81;
        const int gy  = min(max(by0 + row - 8, 0), H - 1);
        const int gx  = min(max(bx0 + col - 8, 0), W - 1);
        GLOAD_LDS4(x + (size_t)gy * W + gx, P + c * 64);
    }
    __syncthreads();   // compiler emits s_waitcnt vmcnt(0) before s_barrier

    // ---- Phase 2a: row prefix, thread t scans row t+1. Reads batched 8-wide
    // so each lgkm wait covers 4 ds_read2 instead of one pair (latency /8).
    if (tid < PT) {
        float v = 0.0f;
        const int rb = (tid + 1) * STRIDE + 1;
        #pragma unroll
        for (int j0 = 0; j0 < 72; j0 += 8) {
            float a0 = P[rb+j0+0], a1 = P[rb+j0+1], a2 = P[rb+j0+2], a3 = P[rb+j0+3];
            float a4 = P[rb+j0+4], a5 = P[rb+j0+5], a6 = P[rb+j0+6], a7 = P[rb+j0+7];
            float v0 = v  + a0, v1 = v0 + a1, v2 = v1 + a2, v3 = v2 + a3;
            float v4 = v3 + a4, v5 = v4 + a5, v6 = v5 + a6, v7 = v6 + a7;
            P[rb+j0+0] = v0; P[rb+j0+1] = v1; P[rb+j0+2] = v2; P[rb+j0+3] = v3;
            P[rb+j0+4] = v4; P[rb+j0+5] = v5; P[rb+j0+6] = v6; P[rb+j0+7] = v7;
            v = v7;
        }
        {   // tail 6 (j = 72..77)
            const int b = rb + 72;
            float a0 = P[b+0], a1 = P[b+1], a2 = P[b+2], a3 = P[b+3], a4 = P[b+4], a5 = P[b+5];
            float v0 = v  + a0, v1 = v0 + a1, v2 = v1 + a2;
            float v3 = v2 + a3, v4 = v3 + a4, v5 = v4 + a5;
            P[b+0] = v0; P[b+1] = v1; P[b+2] = v2; P[b+3] = v3; P[b+4] = v4; P[b+5] = v5;
        }
    } else {
        // ---- Phase 2b (concurrent with the scan): zero the prefix guards.
        // Row 0 (81 dwords) + col 0 of rows 1..78. Disjoint from scan touches.
        const int p = tid - PT;               // 0..177
        if (p < 81)            P[p] = 0.0f;
        else if (p < 81 + 78)  P[(p - 80) * STRIDE] = 0.0f;
    }
    __syncthreads();

    // ---- Phase 3: column prefix, thread t scans column t+1. Groups of 8 rows,
    // two opaque bases keep every (0,81),(162,243)-dword pair ds_read2-mergeable.
    if (tid < PT) {
        float v = 0.0f;
        int cb = STRIDE + (tid + 1);
        #pragma unroll 1
        for (int g = 0; g < 9; ++g) {        // 9 x 8 = 72 rows
            int b0 = cb, b1 = cb + 4 * STRIDE;
            asm volatile("" : "+v"(b0), "+v"(b1));
            float a0 = P[b0],              a1 = P[b0 + STRIDE];
            float a2 = P[b0 + 2*STRIDE],   a3 = P[b0 + 3*STRIDE];
            float a4 = P[b1],              a5 = P[b1 + STRIDE];
            float a6 = P[b1 + 2*STRIDE],   a7 = P[b1 + 3*STRIDE];
            float v0 = v  + a0, v1 = v0 + a1, v2 = v1 + a2, v3 = v2 + a3;
            float v4 = v3 + a4, v5 = v4 + a5, v6 = v5 + a6, v7 = v6 + a7;
            P[b0] = v0;            P[b0 + STRIDE] = v1;
            P[b0 + 2*STRIDE] = v2; P[b0 + 3*STRIDE] = v3;
            P[b1] = v4;            P[b1 + STRIDE] = v5;
            P[b1 + 2*STRIDE] = v6; P[b1 + 3*STRIDE] = v7;
            v = v7;
            cb += 8 * STRIDE;
        }
        {   // tail 6 rows (72..77)
            int b0 = cb, b1 = cb + 4 * STRIDE;
            asm volatile("" : "+v"(b0), "+v"(b1));
            float a0 = P[b0],            a1 = P[b0 + STRIDE];
            float a2 = P[b0 + 2*STRIDE], a3 = P[b0 + 3*STRIDE];
            float a4 = P[b1],            a5 = P[b1 + STRIDE];
            float v0 = v  + a0, v1 = v0 + a1, v2 = v1 + a2;
            float v3 = v2 + a3, v4 = v3 + a4, v5 = v4 + a5;
            P[b0] = v0;            P[b0 + STRIDE] = v1;
            P[b0 + 2*STRIDE] = v2; P[b0 + 3*STRIDE] = v3;
            P[b1] = v4;            P[b1 + STRIDE] = v5;
        }
    }
    __syncthreads();

    // ---- Epilogue: lane owns one column, 16 rows. 28 corner reads per pixel,
    // grouped under 4 opaque bases so every pair (B1,B0) of the same row merges
    // into one ds_read2_b32 (both offsets <= 255 dwords from its base).
    const int lx = tid & 63;
    const int y0 = (tid >> 6) * 16;
    const int gx = bx0 + lx;

    // Prefetch base[] for all 16 rows -> the 16 global loads overlap the
    // LDS-bound corner loop instead of sitting load-use on the critical path.
    float bv[16];
    {
        const float* bp = base + (size_t)(by0 + y0) * W + gx;
        #pragma unroll
        for (int yy = 0; yy < 16; ++yy) bv[yy] = bp[(size_t)yy * W];
    }

    int vb = y0 * STRIDE + lx;
    #pragma unroll
    for (int yy = 0; yy < 16; ++yy) {
        int ia = vb;                        // A0 rows +0..+2   (r = 7,6,5)
        int ib = vb + 3 * STRIDE;           // A0 rows +3..+6   (r = 4,3,2,1)
        int ic = vb + 9 * STRIDE;           // A1 rows +9..+11  (r = 1,2,3)
        int id = vb + 12 * STRIDE + 3;      // A1 rows +12..+15 (r = 4..7), +3 keeps offsets <= 255
        asm volatile("" : "+v"(ia), "+v"(ib), "+v"(ic), "+v"(id));

        float acc = 0.0f;
        #pragma unroll
        for (int r = 1; r <= 7; ++r) {
            const int c0 = 7 - r, c1 = 8 + r;
            float a0b0, a0b1, a1b0, a1b1;
            if (r >= 5) {   // A0 row offset (7-r) in 0..2 from ia
                a0b0 = P[ia + (7 - r) * STRIDE + c0];
                a0b1 = P[ia + (7 - r) * STRIDE + c1];
            } else {        // A0 row offset (7-r) in 3..6 -> (4-r) from ib
                a0b0 = P[ib + (4 - r) * STRIDE + c0];
                a0b1 = P[ib + (4 - r) * STRIDE + c1];
            }
            if (r <= 3) {   // A1 row offset (8+r) in 9..11 -> (r-1) from ic
                a1b0 = P[ic + (r - 1) * STRIDE + c0];
                a1b1 = P[ic + (r - 1) * STRIDE + c1];
            } else {        // A1 row offset (8+r) in 12..15 -> (r-4) from id (shifted +3)
                a1b0 = P[id + (r - 4) * STRIDE + c0 - 3];
                a1b1 = P[id + (r - 4) * STRIDE + c1 - 3];
            }
            const int k = 2 * r + 1;
            const float wk = 1.0f / (7.0f * (float)(k * k));
            acc = fmaf((a1b1 - a1b0) - (a0b1 - a0b0), wk, acc);
        }
        const int g = (by0 + y0 + yy) * W + gx;
        out[g] = acc * bv[yy];
        vb += STRIDE;
    }
}

extern "C" void kernel_launch(void* const* d_in, const int* in_sizes, int n_in,
                              void* d_out, int out_size, void* d_ws, size_t ws_size,
                              hipStream_t stream) {
    const float* x    = (const float*)d_in[0];
    const float* base = (const float*)d_in[1];
    float* out        = (float*)d_out;

    dim3 grid(W / TILE, H / TILE);  // 64 x 64 tiles
    multi_box_kernel<<<grid, 256, 0, stream>>>(x, base, out);
}

// Round 2
// 172.964 us; speedup vs baseline: 1.1130x; 1.0108x over previous
//
#include <hip/hip_runtime.h>

// Problem constants (fixed by setup_inputs: 4096x4096 fp32).
#define H 4096
#define W 4096
#define TILE 64              // block output tile; 4 waves x (32x32) private quarters
#define QT 32                // per-wave quarter tile
#define PADR 7               // max k = 15 -> radius 7
#define QPT (QT + 2 * PADR)  // 46 padded data extent
#define QSTRIDE 49           // odd stride: all LDS access patterns conflict-free
#define QARENA 2304          // 47 rows * 49 + 1 pad dword = 36 chunks of 64
#define NCH 36

// Async global->LDS: dest is wave-uniform base + lane*4 (linear), source per-lane.
#define GLOAD_LDS4(gp, lp) __builtin_amdgcn_global_load_lds(                 \
    (const __attribute__((address_space(1))) void*)(gp),                     \
    (__attribute__((address_space(3))) void*)(lp), 4, 0, 0)

// Wave-autonomous design: each wave owns one 32x32 output quarter with a private
// 47x49 LDS arena. NO __syncthreads anywhere -- all hazards are wave-internal
// (vmcnt for staging, lgkmcnt for LDS RAW), so every resident wave is an
// independent dependency stream and SIMDs always have issueable work.
__global__ __launch_bounds__(256, 4) void multi_box_kernel(
    const float* __restrict__ x,
    const float* __restrict__ base,
    float* __restrict__ out)
{
    __shared__ float Parena[4 * QARENA];   // 36.9 KB -> 4 blocks/CU, 16 indep waves

    const int tid  = threadIdx.x;
    const int lane = tid & 63;
    const int wv   = tid >> 6;
    float* __restrict__ Q = Parena + wv * QARENA;

    // This wave's output quarter origin.
    const int qx0 = blockIdx.x * TILE + (wv & 1) * QT;
    const int qy0 = blockIdx.y * TILE + (wv >> 1) * QT;

    // ---- Phase 1: stage padded 46x46 tile into rows 1..46 / cols 1..46 of the
    // 47x49 arena. dword d: row = d/49, col = d%49; guard row 0 / col 0 and junk
    // cols 47..48 get harmless clamped garbage (guards re-zeroed below).
    // 36 async issues, ONE wave-local vmcnt drain, no barrier.
    #pragma unroll
    for (int ch = 0; ch < NCH; ++ch) {
        const int d   = ch * 64 + lane;
        const int row = d / 49;              // magic-mul, chunk-constant numerand base
        const int col = d - row * 49;
        const int gy  = min(max(qy0 + row - 8, 0), H - 1);  // replicate padding
        const int gx  = min(max(qx0 + col - 8, 0), W - 1);
        GLOAD_LDS4(x + (size_t)gy * W + gx, Q + ch * 64);
    }
    asm volatile("s_waitcnt vmcnt(0)" ::: "memory");
    __builtin_amdgcn_sched_barrier(0);       // rule 18: pin following DS ops after wait

    // ---- Zero the prefix guards (after drain so staged junk can't overwrite them).
    if (lane < 47)              Q[lane] = 0.0f;            // guard row 0
    if (lane >= 1 && lane < 47) Q[lane * QSTRIDE] = 0.0f;  // guard col 0, rows 1..46

    // ---- Phase 2: row prefix. Lane t scans row t+1 (46 elems), batched 8-wide.
    // Lane addr stride 49 dwords -> bank stride 17 (odd) -> conflict-free.
    if (lane < 46) {
        float v = 0.0f;
        const int rb = (lane + 1) * QSTRIDE + 1;
        #pragma unroll
        for (int j0 = 0; j0 < 40; j0 += 8) {
            float a0 = Q[rb+j0+0], a1 = Q[rb+j0+1], a2 = Q[rb+j0+2], a3 = Q[rb+j0+3];
            float a4 = Q[rb+j0+4], a5 = Q[rb+j0+5], a6 = Q[rb+j0+6], a7 = Q[rb+j0+7];
            float v0 = v  + a0, v1 = v0 + a1, v2 = v1 + a2, v3 = v2 + a3;
            float v4 = v3 + a4, v5 = v4 + a5, v6 = v5 + a6, v7 = v6 + a7;
            Q[rb+j0+0] = v0; Q[rb+j0+1] = v1; Q[rb+j0+2] = v2; Q[rb+j0+3] = v3;
            Q[rb+j0+4] = v4; Q[rb+j0+5] = v5; Q[rb+j0+6] = v6; Q[rb+j0+7] = v7;
            v = v7;
        }
        {   // tail 6 (j = 40..45)
            const int b = rb + 40;
            float a0 = Q[b+0], a1 = Q[b+1], a2 = Q[b+2], a3 = Q[b+3], a4 = Q[b+4], a5 = Q[b+5];
            float v0 = v  + a0, v1 = v0 + a1, v2 = v1 + a2;
            float v3 = v2 + a3, v4 = v3 + a4, v5 = v4 + a5;
            Q[b+0] = v0; Q[b+1] = v1; Q[b+2] = v2; Q[b+3] = v3; Q[b+4] = v4; Q[b+5] = v5;
        }
    }

    // ---- Phase 3: column prefix. Lane t scans col t+1 (46 rows), groups of 8
    // with two opaque bases so every (0,49),(98,147)-pair merges into ds_read2.
    // Lane addr stride 1 -> conflict-free. RAW vs phase 2 ordered by lgkmcnt.
    if (lane < 46) {
        float v = 0.0f;
        int cb = QSTRIDE + (lane + 1);
        #pragma unroll 1
        for (int g = 0; g < 5; ++g) {        // 5 x 8 = 40 rows
            int b0 = cb, b1 = cb + 4 * QSTRIDE;
            asm volatile("" : "+v"(b0), "+v"(b1));
            float a0 = Q[b0],               a1 = Q[b0 + QSTRIDE];
            float a2 = Q[b0 + 2*QSTRIDE],   a3 = Q[b0 + 3*QSTRIDE];
            float a4 = Q[b1],               a5 = Q[b1 + QSTRIDE];
            float a6 = Q[b1 + 2*QSTRIDE],   a7 = Q[b1 + 3*QSTRIDE];
            float v0 = v  + a0, v1 = v0 + a1, v2 = v1 + a2, v3 = v2 + a3;
            float v4 = v3 + a4, v5 = v4 + a5, v6 = v5 + a6, v7 = v6 + a7;
            Q[b0] = v0;             Q[b0 + QSTRIDE] = v1;
            Q[b0 + 2*QSTRIDE] = v2; Q[b0 + 3*QSTRIDE] = v3;
            Q[b1] = v4;             Q[b1 + QSTRIDE] = v5;
            Q[b1 + 2*QSTRIDE] = v6; Q[b1 + 3*QSTRIDE] = v7;
            v = v7;
            cb += 8 * QSTRIDE;
        }
        {   // tail 6 rows (41..46)
            int b0 = cb, b1 = cb + 4 * QSTRIDE;
            asm volatile("" : "+v"(b0), "+v"(b1));
            float a0 = Q[b0],             a1 = Q[b0 + QSTRIDE];
            float a2 = Q[b0 + 2*QSTRIDE], a3 = Q[b0 + 3*QSTRIDE];
            float a4 = Q[b1],             a5 = Q[b1 + QSTRIDE];
            float v0 = v  + a0, v1 = v0 + a1, v2 = v1 + a2;
            float v3 = v2 + a3, v4 = v3 + a4, v5 = v4 + a5;
            Q[b0] = v0;             Q[b0 + QSTRIDE] = v1;
            Q[b0 + 2*QSTRIDE] = v2; Q[b0 + 3*QSTRIDE] = v3;
            Q[b1] = v4;             Q[b1 + QSTRIDE] = v5;
        }
    }

    // ---- Epilogue: lane (c,h) owns column c, rows h*16..h*16+15 of the quarter.
    // 28 corner reads per pixel under 4 opaque bases -> all pairs ds_read2-merge
    // (every offset <= 211 dwords). Lane addr stride 1 -> conflict-free.
    const int c   = lane & 31;
    const int hh  = lane >> 5;
    const int y0  = hh * 16;
    const int gx  = qx0 + c;
    const int gy0 = qy0 + y0;

    // Prefetch base[] so those 16 global loads overlap the LDS-bound corner loop.
    float bv[16];
    {
        const float* bp = base + (size_t)gy0 * W + gx;
        #pragma unroll
        for (int yy = 0; yy < 16; ++yy) bv[yy] = bp[(size_t)yy * W];
    }

    int vb = y0 * QSTRIDE + c;
    #pragma unroll
    for (int yy = 0; yy < 16; ++yy) {
        int ia = vb;                    // rows +0..+4   (A0, r = 7..3)
        int ib = vb + 5 * QSTRIDE;      // rows +5..+6   (A0, r = 2,1)
        int ic = vb + 9 * QSTRIDE;      // rows +9..+13  (A1, r = 1..5)
        int id = vb + 14 * QSTRIDE;     // rows +14..+15 (A1, r = 6,7)
        asm volatile("" : "+v"(ia), "+v"(ib), "+v"(ic), "+v"(id));

        float acc = 0.0f;
        #pragma unroll
        for (int r = 1; r <= 7; ++r) {
            const int c0 = 7 - r, c1 = 8 + r;
            float a0b0, a0b1, a1b0, a1b1;
            if (r >= 3) {   // A0 row offset (7-r) in 0..4 from ia
                a0b0 = Q[ia + (7 - r) * QSTRIDE + c0];
                a0b1 = Q[ia + (7 - r) * QSTRIDE + c1];
            } else {        // A0 row offset (7-r) in 5..6 -> (2-r) from ib
                a0b0 = Q[ib + (2 - r) * QSTRIDE + c0];
                a0b1 = Q[ib + (2 - r) * QSTRIDE + c1];
            }
            if (r <= 5) {   // A1 row offset (8+r) in 9..13 -> (r-1) from ic
                a1b0 = Q[ic + (r - 1) * QSTRIDE + c0];
                a1b1 = Q[ic + (r - 1) * QSTRIDE + c1];
            } else {        // A1 row offset (8+r) in 14..15 -> (r-6) from id
                a1b0 = Q[id + (r - 6) * QSTRIDE + c0];
                a1b1 = Q[id + (r - 6) * QSTRIDE + c1];
            }
            const int k = 2 * r + 1;
            const float wk = 1.0f / (7.0f * (float)(k * k));
            acc = fmaf((a1b1 - a1b0) - (a0b1 - a0b0), wk, acc);
        }
        out[(size_t)(gy0 + yy) * W + gx] = acc * bv[yy];
        vb += QSTRIDE;
    }
}

extern "C" void kernel_launch(void* const* d_in, const int* in_sizes, int n_in,
                              void* d_out, int out_size, void* d_ws, size_t ws_size,
                              hipStream_t stream) {
    const float* x    = (const float*)d_in[0];
    const float* base = (const float*)d_in[1];
    float* out        = (float*)d_out;

    dim3 grid(W / TILE, H / TILE);  // 64 x 64 blocks, 4 autonomous waves each
    multi_box_kernel<<<grid, 256, 0, stream>>>(x, base, out);
}

// Round 3
// 170.015 us; speedup vs baseline: 1.1323x; 1.0173x over previous
//
#include <hip/hip_runtime.h>

// Problem constants (fixed by setup_inputs: 4096x4096 fp32).
#define H 4096
#define W 4096
#define TILE 64              // block output tile; 4 waves x (32x32) private quarters
#define QT 32                // per-wave quarter tile
#define QROWS 46             // padded rows: 32 + 2*7 (NO guard row needed: row-prefix only)
#define QSTRIDE 49           // guard col 0 + 46 data cols + 2 junk; odd stride
#define QARENA 2304          // 46*49 = 2254 -> padded to 36 chunks * 64 (junk tail in-arena)
#define NCH 36

// Async global->LDS: dest is wave-uniform base + lane*4 (linear), source per-lane.
#define GLOAD_LDS4(gp, lp) __builtin_amdgcn_global_load_lds(                 \
    (const __attribute__((address_space(1))) void*)(gp),                     \
    (__attribute__((address_space(3))) void*)(lp), 4, 0, 0)

// Wave-autonomous, row-prefix-only design. Each wave owns a 32x32 output
// quarter with a private 46x49 LDS arena holding the ROW prefix sums R only.
// The column dimension is handled per-lane with running box sums and a
// 63-register FIFO of D_k values (D_k(a) = R(a,c1)-R(a,c0)), halving the
// epilogue's LDS reads (7 ds_read2/pixel vs 14) and deleting the column-scan
// phase. No __syncthreads anywhere; all hazards wave-internal.
__global__ __launch_bounds__(256, 4) void multi_box_kernel(
    const float* __restrict__ x,
    const float* __restrict__ base,
    float* __restrict__ out)
{
    __shared__ float Parena[4 * QARENA];   // 36.9 KB -> 4 blocks/CU, 16 indep waves

    const int tid  = threadIdx.x;
    const int lane = tid & 63;
    const int wv   = tid >> 6;
    float* __restrict__ Q = Parena + wv * QARENA;

    // This wave's output quarter origin.
    const int qx0 = blockIdx.x * TILE + (wv & 1) * QT;
    const int qy0 = blockIdx.y * TILE + (wv >> 1) * QT;

    // ---- Phase 1: stage padded 46x46 tile. Arena row a = padded-tile row a
    // (global gy = qy0 + a - 7), data cols at arena cols 1..46 (gx = qx0+col-8).
    // Guard col 0 / junk cols 47..48 / tail dwords get clamped garbage.
    #pragma unroll
    for (int ch = 0; ch < NCH; ++ch) {
        const int d   = ch * 64 + lane;
        const int row = d / 49;              // magic-mul
        const int col = d - row * 49;
        const int gy  = min(max(qy0 + row - 7, 0), H - 1);  // replicate padding
        const int gx  = min(max(qx0 + col - 8, 0), W - 1);
        GLOAD_LDS4(x + (size_t)gy * W + gx, Q + ch * 64);
    }
    asm volatile("s_waitcnt vmcnt(0)" ::: "memory");
    __builtin_amdgcn_sched_barrier(0);       // rule 18: pin following DS ops after wait

    // ---- Zero guard col 0 (rows 0..45) after the drain.
    if (lane < QROWS) Q[lane * QSTRIDE] = 0.0f;

    // ---- Phase 2: row prefix. Lane t scans row t (46 elems, cols 1..46),
    // batched 8-wide. Lane addr stride 49 -> bank stride 17 -> conflict-free.
    if (lane < QROWS) {
        float v = 0.0f;
        const int rb = lane * QSTRIDE + 1;
        #pragma unroll
        for (int j0 = 0; j0 < 40; j0 += 8) {
            float a0 = Q[rb+j0+0], a1 = Q[rb+j0+1], a2 = Q[rb+j0+2], a3 = Q[rb+j0+3];
            float a4 = Q[rb+j0+4], a5 = Q[rb+j0+5], a6 = Q[rb+j0+6], a7 = Q[rb+j0+7];
            float v0 = v  + a0, v1 = v0 + a1, v2 = v1 + a2, v3 = v2 + a3;
            float v4 = v3 + a4, v5 = v4 + a5, v6 = v5 + a6, v7 = v6 + a7;
            Q[rb+j0+0] = v0; Q[rb+j0+1] = v1; Q[rb+j0+2] = v2; Q[rb+j0+3] = v3;
            Q[rb+j0+4] = v4; Q[rb+j0+5] = v5; Q[rb+j0+6] = v6; Q[rb+j0+7] = v7;
            v = v7;
        }
        {   // tail 6 (j = 40..45)
            const int b = rb + 40;
            float a0 = Q[b+0], a1 = Q[b+1], a2 = Q[b+2], a3 = Q[b+3], a4 = Q[b+4], a5 = Q[b+5];
            float v0 = v  + a0, v1 = v0 + a1, v2 = v1 + a2;
            float v3 = v2 + a3, v4 = v3 + a4, v5 = v4 + a5;
            Q[b+0] = v0; Q[b+1] = v1; Q[b+2] = v2; Q[b+3] = v3; Q[b+4] = v4; Q[b+5] = v5;
        }
    }

    // ---- Epilogue: lane (pc, hh) owns column pc, rows hh*16..hh*16+15.
    // For pixel row ry, kernel radius r: window = arena rows [ry+7-r, ry+7+r],
    // cols (c0,c1) = (pc+7-r, pc+8+r). D_k(a) = Q[a*49+c1] - Q[a*49+c0]
    // (one ds_read2). box_k slides down the column: += D(new) - D(old<ring>).
    const int pc  = lane & 31;
    const int hh  = lane >> 5;
    const int y0  = hh * 16;
    const int gx  = qx0 + pc;
    const int gy0 = qy0 + y0;

    float box[7] = {0.f, 0.f, 0.f, 0.f, 0.f, 0.f, 0.f};
    float ring[63];   // per-k FIFO, base RB(kk)=kk*kk+2*kk, depth 2kk+3; all
                      // indices compile-time under full unroll -> stays in VGPRs

    // ---- Init: rows o = 0..14 feed the r >= |o-7| rings; 63 ds_read2 total.
    #pragma unroll
    for (int g = 0; g < 3; ++g) {
        int gb = (y0 + g * 5) * QSTRIDE + pc;
        asm volatile("" : "+v"(gb));         // opaque base: offsets <= 211 dwords
        #pragma unroll
        for (int oo = 0; oo < 5; ++oo) {
            const int o = g * 5 + oo;
            #pragma unroll
            for (int kk = 0; kk < 7; ++kk) {
                const int r = kk + 1;
                if (o < 7 - r || o > 7 + r) continue;   // compile-time pruned
                float lo = Q[gb + oo * QSTRIDE + (7 - r)];
                float hi = Q[gb + oo * QSTRIDE + (8 + r)];
                float D  = hi - lo;
                ring[kk * kk + 2 * kk + (o - (7 - r))] = D;
                box[kk] += D;
            }
        }
    }

    // Prefetch base[] now (after init's register peak) -> overlaps the step loop.
    float bv[16];
    {
        const float* bp = base + (size_t)gy0 * W + gx;
        #pragma unroll
        for (int yy = 0; yy < 16; ++yy) bv[yy] = bp[(size_t)yy * W];
    }

    // ---- Pixel yy = 0 straight from the init boxes.
    {
        float acc = 0.f;
        #pragma unroll
        for (int kk = 0; kk < 7; ++kk) {
            const int k = 2 * kk + 3;
            acc = fmaf(box[kk], 1.0f / (7.0f * (float)(k * k)), acc);
        }
        out[(size_t)gy0 * W + gx] = acc * bv[0];
    }

    // ---- Steps yy = 1..15: per k one new D (ds_read2), old D from the ring.
    #pragma unroll
    for (int yy = 1; yy < 16; ++yy) {
        int nb1 = (y0 + yy + 8)  * QSTRIDE + pc;   // rows for r=1..5 (+0..4 rows)
        int nb2 = (y0 + yy + 13) * QSTRIDE + pc;   // rows for r=6,7  (+0..1 rows)
        asm volatile("" : "+v"(nb1), "+v"(nb2));   // max offsets 209 / 64 dwords
        float acc = 0.f;
        #pragma unroll
        for (int kk = 0; kk < 7; ++kk) {
            const int r = kk + 1;
            float lo, hi;
            if (r <= 5) {
                lo = Q[nb1 + (r - 1) * QSTRIDE + (7 - r)];
                hi = Q[nb1 + (r - 1) * QSTRIDE + (8 + r)];
            } else {
                lo = Q[nb2 + (r - 6) * QSTRIDE + (7 - r)];
                hi = Q[nb2 + (r - 6) * QSTRIDE + (8 + r)];
            }
            float D = hi - lo;
            const int slot = (yy - 1) % (2 * r + 1);   // compile-time
            const int ri   = kk * kk + 2 * kk + slot;
            box[kk] += D - ring[ri];
            ring[ri] = D;
            const int k = 2 * r + 1;
            acc = fmaf(box[kk], 1.0f / (7.0f * (float)(k * k)), acc);
        }
        out[(size_t)(gy0 + yy) * W + gx] = acc * bv[yy];
    }
}

extern "C" void kernel_launch(void* const* d_in, const int* in_sizes, int n_in,
                              void* d_out, int out_size, void* d_ws, size_t ws_size,
                              hipStream_t stream) {
    const float* x    = (const float*)d_in[0];
    const float* base = (const float*)d_in[1];
    float* out        = (float*)d_out;

    dim3 grid(W / TILE, H / TILE);  // 64 x 64 blocks, 4 autonomous waves each
    multi_box_kernel<<<grid, 256, 0, stream>>>(x, base, out);
}